// Round 18
// baseline (128.058 us; speedup 1.0000x reference)
//
#include <hip/hip_runtime.h>

typedef unsigned int uint_t;
typedef unsigned long long u64;
typedef unsigned short u16;
typedef __attribute__((ext_vector_type(4))) float f32x4;
typedef __attribute__((ext_vector_type(16))) float f32x16;
typedef __attribute__((ext_vector_type(8))) __bf16 bf16x8;

#define S_TOT 20000
#define S_LD  20032   // padded V^T row stride / padded K rows
#define B_TOT 1024
#define NHEAD 4
#define NSPLIT 32
#define NCHUNK 313    // ceil(20000/64)
#define NGRP   79     // ceil(20000/256) pack groups (4 chunks each)

__device__ __forceinline__ u16 f2bf(float x) {
  uint_t u = __builtin_bit_cast(uint_t, x);
  u += 0x7FFFu + ((u >> 16) & 1u);
  return (u16)(u >> 16);
}

__device__ __forceinline__ uint_t cvtpk(float lo, float hi) {
  uint_t r;
  asm("v_cvt_pk_bf16_f32 %0, %1, %2" : "=v"(r) : "v"(lo), "v"(hi));
  return r;
}

__device__ __forceinline__ bf16x8 ld_frag(const void* p) {
  return __builtin_bit_cast(bf16x8, *(const uint4*)p);
}

__device__ __forceinline__ void gload_lds16(const void* g, void* l) {
  __builtin_amdgcn_global_load_lds((const __attribute__((address_space(1))) unsigned int*)g,
                                   (__attribute__((address_space(3))) unsigned int*)l, 16, 0, 0);
}

// ---------------- fused prep: weight/nc/emb convert + mask pack (int4) + vt pad zero --------
// blocks [0,448): convert ipw (196608 f32) then nc (262144 f32) via float4.
// blocks [448,5448): convert emb (5.12M f32).
// blocks [5448,25672): mask pack (int4 + nibble shuffle-OR -> pmT, R9 format).
// blocks [25672,25704): zero V^T pad columns.
__global__ void pack_conv(const int* __restrict__ act, u64* __restrict__ pmT,
                          const float* __restrict__ ipw, const float* __restrict__ nc,
                          const float* __restrict__ emb,
                          u16* __restrict__ wqkv, u16* __restrict__ ncb,
                          u16* __restrict__ embb, u16* __restrict__ vt) {
  const int bx = blockIdx.x;
  if (bx < 5448) {
    const float* src; u16* dst;
    if (bx < 448) {
      int i = (bx * 256 + threadIdx.x) * 4;
      if (i < 196608) { src = ipw + i;            dst = wqkv + i; }
      else            { src = nc + (i - 196608);  dst = ncb + (i - 196608); }
    } else {
      int i = ((bx - 448) * 256 + threadIdx.x) * 4;
      src = emb + i; dst = embb + i;
    }
    float4 v = *(const float4*)src;
    uint2 o;
    o.x = f2bf(v.x) | ((uint_t)f2bf(v.y) << 16);
    o.y = f2bf(v.z) | ((uint_t)f2bf(v.w) << 16);
    *(uint2*)dst = o;
    return;
  }
  if (bx < 25672) {
    const int gw = (bx - 5448) * 4 + (threadIdx.x >> 6);   // 0 .. 80896 = 1024 rows * 79 grps
    const int lane = threadIdx.x & 63;
    const int row = gw / NGRP, gi = gw - row * NGRP;
    const int s = gi * 256 + lane * 4;
    int4 v = make_int4(0, 0, 0, 0);
    if (s < S_TOT) v = *(const int4*)(act + (size_t)row * S_TOT + s);
    uint_t nib = (v.x > 0 ? 1u : 0u) | (v.y > 0 ? 2u : 0u) |
                 (v.z > 0 ? 4u : 0u) | (v.w > 0 ? 8u : 0u);
    u64 v64 = (u64)nib << (4 * (lane & 15));
    v64 |= __shfl_xor(v64, 1);
    v64 |= __shfl_xor(v64, 2);
    v64 |= __shfl_xor(v64, 4);
    v64 |= __shfl_xor(v64, 8);
    if ((lane & 15) == 0)     // lanes 0,16,32,48 -> chunks gi*4 + 0..3 (pmT padded to 316)
      pmT[(size_t)(gi * 4 + (lane >> 4)) * B_TOT + row] = v64;
    return;
  }
  int i = (bx - 25672) * 256 + threadIdx.x;       // 8192 = 256 rows * 32
  int d = i >> 5, j = i & 31;
  vt[(size_t)d * S_LD + S_TOT + j] = 0;
}

// ---------------- KV + Q projection: fused 128x64-tile GEMM ----------------
// y in [0,8): C[20000 x 512] = embb @ Wkv^T + b  (K rows / V^T)
// y in [8,12): C[1024 x 256] = ncb @ Wq^T + b, scaled bf16 -> qb  (x < 8 only)
__launch_bounds__(256, 3)
__global__ void gemm_kvq(const u16* __restrict__ embb, const u16* __restrict__ ncb,
                         const u16* __restrict__ wqkv, const float* __restrict__ ipb,
                         u16* __restrict__ kb, u16* __restrict__ vtb, u16* __restrict__ qb,
                         float qsc) {
  const int by = blockIdx.y;
  const int qmode = (by >= 8);
  if (qmode && blockIdx.x >= 8) return;
  __shared__ __align__(16) u16 sA[2][128][64];
  __shared__ __align__(16) u16 sW[2][64][64];
  const int t = threadIdx.x, w = t >> 6, lane = t & 63;
  const int q5 = lane & 31, hi = lane >> 5;
  const int wr = w >> 1, wc = w & 1;
  const int m0 = blockIdx.x * 128;
  const int M = qmode ? B_TOT : S_TOT;
  const u16* A = qmode ? ncb : embb;
  const int wrow0 = qmode ? (by - 8) * 64 : 256 + by * 64;   // row base in wqkv
  const u16* W = wqkv + (size_t)wrow0 * 256;
  const float* bias = ipb + wrow0;

  auto stage = [&](int buf, int k0) {
#pragma unroll
    for (int j = 0; j < 4; j++) {           // A: 1024 16B-chunks
      int c = j * 256 + w * 64 + lane;
      int row = c >> 3, slot = c & 7;
      int gm = m0 + row; if (gm > M - 1) gm = M - 1;
      gload_lds16(A + (size_t)gm * 256 + k0 + ((slot ^ (row & 7)) * 8),
                  &sA[buf][0][0] + (size_t)(j * 256 + w * 64) * 8);
    }
#pragma unroll
    for (int j = 0; j < 2; j++) {           // W: 512 16B-chunks
      int c = j * 256 + w * 64 + lane;
      int row = c >> 3, slot = c & 7;
      gload_lds16(W + (size_t)row * 256 + k0 + ((slot ^ (row & 7)) * 8),
                  &sW[buf][0][0] + (size_t)(j * 256 + w * 64) * 8);
    }
  };

  f32x16 acc[2] = {{}, {}};
  stage(0, 0);
  __syncthreads();
  for (int ks = 0; ks < 4; ks++) {
    const int buf = ks & 1;
    if (ks < 3) stage(buf ^ 1, (ks + 1) * 64);
#pragma unroll
    for (int k4 = 0; k4 < 4; k4++) {
      const int rowW = wc * 32 + q5;
      bf16x8 wf = ld_frag(&sW[buf][rowW][((2 * k4 + hi) ^ (rowW & 7)) * 8]);
#pragma unroll
      for (int blk = 0; blk < 2; blk++) {
        const int rowA = wr * 64 + blk * 32 + q5;
        bf16x8 af = ld_frag(&sA[buf][rowA][((2 * k4 + hi) ^ (rowA & 7)) * 8]);
        acc[blk] = __builtin_amdgcn_mfma_f32_32x32x16_bf16(af, wf, acc[blk], 0, 0, 0);
      }
    }
    __syncthreads();
  }
  const int nl = wc * 32 + q5;              // local col within 64-tile
  const float bi = bias[nl];
  if (qmode) {
    const int n = (by - 8) * 64 + nl;       // 0..255
#pragma unroll
    for (int blk = 0; blk < 2; blk++)
#pragma unroll
      for (int r = 0; r < 16; r++) {
        int mrow = m0 + wr * 64 + blk * 32 + (r & 3) + 8 * (r >> 2) + 4 * hi;
        if (mrow < B_TOT) qb[(size_t)mrow * 256 + n] = f2bf((acc[blk][r] + bi) * qsc);
      }
    return;
  }
  const int n = by * 64 + nl;               // 0..511
  if (n < 256) {
#pragma unroll
    for (int blk = 0; blk < 2; blk++)
#pragma unroll
      for (int r = 0; r < 16; r++) {
        int mrow = m0 + wr * 64 + blk * 32 + (r & 3) + 8 * (r >> 2) + 4 * hi;
        if (mrow < S_TOT) kb[(size_t)mrow * 256 + n] = f2bf(acc[blk][r] + bi);
      }
  } else {
    const int vr = n - 256;
#pragma unroll
    for (int blk = 0; blk < 2; blk++)
#pragma unroll
      for (int g = 0; g < 4; g++) {
        int mb = m0 + wr * 64 + blk * 32 + 8 * g + 4 * hi;
        u16 b4[4];
#pragma unroll
        for (int j = 0; j < 4; j++) b4[j] = f2bf(acc[blk][4 * g + j] + bi);
        if (mb + 3 < S_TOT) {
          uint2 p2; p2.x = b4[0] | ((uint_t)b4[1] << 16); p2.y = b4[2] | ((uint_t)b4[3] << 16);
          *(uint2*)&vtb[(size_t)vr * S_LD + mb] = p2;
        } else {
#pragma unroll
          for (int j = 0; j < 4; j++) if (mb + j < S_TOT) vtb[(size_t)vr * S_LD + mb + j] = b4[j];
        }
      }
  }
}

// ---------------- flash attention: R13-exact body and layouts (proven 48.5 us) --------------
// Fixed-ref softmax; PV via permlane + 32x32x16; l = mfma(ones, P) -> accl[0].
// pc layout [si][b][h][d] (scattered 4B stores — measured optimal: WRITE ~= payload).
__launch_bounds__(256)
__attribute__((amdgpu_waves_per_eu(4, 4)))
__global__ void attn_k(const u16* __restrict__ qb, const u16* __restrict__ kb,
                       const u16* __restrict__ vt, const u64* __restrict__ pmT,
                       float* __restrict__ pc, float* __restrict__ pl) {
  __shared__ __align__(16) u16 sK[2][64][64];
  __shared__ __align__(16) u16 sV[2][64][64];
  const int t = threadIdx.x;
  const int w = t >> 6, lane = t & 63;
  const int q5 = lane & 31, hi = lane >> 5;
  const int si = blockIdx.x, bt = blockIdx.y, h = blockIdx.z;
  const int qrow = bt * 128 + w * 32 + q5;

  bf16x8 qf[4];
#pragma unroll
  for (int kc = 0; kc < 4; kc++)
    qf[kc] = ld_frag(qb + (size_t)qrow * 256 + h * 64 + kc * 16 + hi * 8);

  f32x16 ctx[2] = {{}, {}};
  f32x16 accl = {};                          // ones-row denominator accumulator
  const uint_t one2 = 0x3F803F80u;           // 2 x bf16 1.0
  uint4 onesw; onesw.x = one2; onesw.y = one2; onesw.z = one2; onesw.w = one2;
  const bf16x8 onesf = __builtin_bit_cast(bf16x8, onesw);

  const int rg = w * 16 + (lane >> 3);
  const int c16 = (lane & 7) ^ ((lane >> 3) & 7);
  const u16* kst = kb + (size_t)(si * 64 + rg) * 256 + h * 64 + c16 * 8;
  const u16* vst = vt + (size_t)(h * 64 + rg) * S_LD + si * 64 + c16 * 8;
  const u64* mptr = pmT + (size_t)si * B_TOT + qrow;
  const size_t KSTEP = (size_t)NSPLIT * 64 * 256;
  const int    VSTEP = NSPLIT * 64;
  const size_t MSTEP = (size_t)NSPLIT * B_TOT;

  auto stage = [&](int buf) {
    gload_lds16(kst,            &sK[buf][w * 16][0]);
    gload_lds16(kst + 8 * 256,  &sK[buf][w * 16 + 8][0]);
    gload_lds16(vst,            &sV[buf][w * 16][0]);
    gload_lds16(vst + 8 * S_LD, &sV[buf][w * 16 + 8][0]);
    kst += KSTEP; vst += VSTEP;
  };

  auto body = [&](int buf) {
    const u64 m64 = *mptr; mptr += MSTEP;
    f32x16 sc0 = {}, sc1 = {};
#pragma unroll
    for (int kc = 0; kc < 4; kc++) {
      const int slot = ((2 * kc + hi) ^ (q5 & 7)) * 8;
      bf16x8 ka0 = ld_frag(&sK[buf][q5][slot]);
      bf16x8 ka1 = ld_frag(&sK[buf][32 + q5][slot]);
      sc0 = __builtin_amdgcn_mfma_f32_32x32x16_bf16(ka0, qf[kc], sc0, 0, 0, 0);
      sc1 = __builtin_amdgcn_mfma_f32_32x32x16_bf16(ka1, qf[kc], sc1, 0, 0, 0);
    }
    const uint_t mw0 = (uint_t)(m64 >> (4 * hi));
    const uint_t mw1 = (uint_t)(m64 >> (32 + 4 * hi));
#pragma unroll
    for (int r = 0; r < 16; r++) {
      const uint_t bsel = 1u << ((r & 3) + 8 * (r >> 2));
      sc0[r] = (mw0 & bsel) ? sc0[r] : -1e9f;
      sc1[r] = (mw1 & bsel) ? sc1[r] : -1e9f;
    }
    uint2 pk[2][4];
#pragma unroll
    for (int j = 0; j < 4; j++) {
      float a0 = exp2f(sc0[4 * j + 0]), a1 = exp2f(sc0[4 * j + 1]);
      float a2 = exp2f(sc0[4 * j + 2]), a3 = exp2f(sc0[4 * j + 3]);
      float b0 = exp2f(sc1[4 * j + 0]), b1 = exp2f(sc1[4 * j + 1]);
      float b2 = exp2f(sc1[4 * j + 2]), b3 = exp2f(sc1[4 * j + 3]);
      pk[0][j].x = cvtpk(a0, a1); pk[0][j].y = cvtpk(a2, a3);
      pk[1][j].x = cvtpk(b0, b1); pk[1][j].y = cvtpk(b2, b3);
    }
    const u16* Vrow = &sV[buf][q5][0];
#pragma unroll
    for (int u = 0; u < 4; u++) {
      const int b = u >> 1, v = u & 1;
      uint_t a0 = pk[b][2 * v].x,     a1 = pk[b][2 * v].y;
      uint_t b0 = pk[b][2 * v + 1].x, b1 = pk[b][2 * v + 1].y;
      asm("v_permlane32_swap_b32 %0, %1" : "+v"(a0), "+v"(b0));
      asm("v_permlane32_swap_b32 %0, %1" : "+v"(a1), "+v"(b1));
      uint4 bw; bw.x = a0; bw.y = a1; bw.z = b0; bw.w = b1;
      bf16x8 pfrag = __builtin_bit_cast(bf16x8, bw);
      const int slot = ((2 * u + hi) ^ (q5 & 7)) * 8;   // u16 units (16B slots)
      bf16x8 va0 = ld_frag(Vrow + slot);
      bf16x8 va1 = ld_frag(Vrow + 32 * 64 + slot);      // row q5+32
      ctx[0] = __builtin_amdgcn_mfma_f32_32x32x16_bf16(va0, pfrag, ctx[0], 0, 0, 0);
      ctx[1] = __builtin_amdgcn_mfma_f32_32x32x16_bf16(va1, pfrag, ctx[1], 0, 0, 0);
      accl   = __builtin_amdgcn_mfma_f32_32x32x16_bf16(onesf, pfrag, accl, 0, 0, 0);
    }
  };

  stage(0);
  __syncthreads();
  int ci = si;
  for (;;) {
    if (ci + NSPLIT < NCHUNK) stage(1);
    body(0);
    __syncthreads();
    ci += NSPLIT;
    if (ci >= NCHUNK) break;
    if (ci + NSPLIT < NCHUNK) stage(0);
    body(1);
    __syncthreads();
    ci += NSPLIT;
    if (ci >= NCHUNK) break;
  }

  size_t obase = (((size_t)si * B_TOT + qrow) * NHEAD + h) * 64;
#pragma unroll
  for (int dc = 0; dc < 2; dc++)
#pragma unroll
    for (int r = 0; r < 16; r++) {
      int d = dc * 32 + (r & 3) + 8 * (r >> 2) + 4 * hi;
      pc[obase + d] = ctx[dc][r];
    }
  if (lane < 32)
    pl[((size_t)si * B_TOT + qrow) * NHEAD + h] = accl[0];   // l = sum of rounded p
}

// ---------------- combine + out-proj fused: block per b ----------------
// Phase 1 (R13-exact sums + lazy v_mean) -> ctx row (f32) in LDS.
// Phase 2: out[b][t] = opb[t] + sum_c ctxrow[c] * opw[t][c]  (f32, like reference).
__global__ void combine_out(const float* __restrict__ pc, const float* __restrict__ pl,
                            const u16* __restrict__ vtb,
                            const float* __restrict__ opw, const float* __restrict__ opb,
                            float* __restrict__ out) {
  __shared__ float ctxrow[256];
  const int b = blockIdx.x, t = threadIdx.x;
  const int h = t >> 6, d = t & 63;
  float L = 0.f, a = 0.f;
#pragma unroll 8
  for (int si = 0; si < NSPLIT; si++) {
    size_t base = ((size_t)si * B_TOT + b) * NHEAD + h;
    L += pl[base];
    a += pc[(base << 6) + d];
  }
  float vmv = 0.f;
  if (__builtin_expect(L == 0.f, 0)) {   // exact fallback; never taken for this data
    float s = 0.f;
    for (int c = 0; c < 2504; c++) {
      bf16x8 v = ld_frag(vtb + (size_t)(h * 64 + d) * S_LD + c * 8);
#pragma unroll
      for (int i = 0; i < 8; i++) s += (float)v[i];
    }
    vmv = s * (1.0f / 20000.0f);
  }
  ctxrow[t] = (L == 0.f) ? vmv : (a / L);
  __syncthreads();
  const float* wrow = opw + (size_t)t * 256;
  float acc = opb[t];
#pragma unroll 4
  for (int c = 0; c < 256; c += 4) {
    float4 wv = *(const float4*)(wrow + c);
    acc += ctxrow[c] * wv.x + ctxrow[c + 1] * wv.y + ctxrow[c + 2] * wv.z + ctxrow[c + 3] * wv.w;
  }
  out[(size_t)b * 256 + t] = acc;
}

// ---------------- launch ----------------
extern "C" void kernel_launch(void* const* d_in, const int* in_sizes, int n_in,
                              void* d_out, int out_size, void* d_ws, size_t ws_size,
                              hipStream_t stream) {
  const int*   act = (const int*)d_in[0];
  const float* nc  = (const float*)d_in[1];
  const float* emb = (const float*)d_in[2];
  const float* ipw = (const float*)d_in[3];
  const float* ipb = (const float*)d_in[4];
  const float* opw = (const float*)d_in[5];
  const float* opb = (const float*)d_in[6];
  float* out = (float*)d_out;
  char* ws = (char*)d_ws;

  size_t off = 0;
  auto alloc = [&](size_t bytes) { size_t r0 = off; off = (off + bytes + 255) & ~(size_t)255; return r0; };
  u16*   wqkv = (u16*)(ws + alloc(768 * 256 * 2));
  u16*   ncb  = (u16*)(ws + alloc((size_t)B_TOT * 256 * 2));
  u16*   qb   = (u16*)(ws + alloc((size_t)B_TOT * 256 * 2));
  u16*   kbuf = (u16*)(ws + alloc((size_t)S_LD * 256 * 2));   // padded rows
  u16*   vtb  = (u16*)(ws + alloc((size_t)256 * S_LD * 2));
  float* pl   = (float*)(ws + alloc((size_t)NSPLIT * B_TOT * NHEAD * 4));
  u64*   pmT  = (u64*)(ws + alloc((size_t)NGRP * 4 * B_TOT * 8));  // 316 chunks (tail pad)
  // union region: embb (10.25 MB, dead after kv-projection) overlaid by pc (33.6 MB)
  size_t ubase = off;
  u16*   embb = (u16*)(ws + ubase);
  float* pc   = (float*)(ws + ubase);

  const float QSC = 0.125f * 1.44269504089f;   // (1/sqrt(64)) * log2(e), folded into Q

  pack_conv<<<25704, 256, 0, stream>>>(act, pmT, ipw, nc, emb, wqkv, ncb, embb, vtb);
  gemm_kvq<<<dim3(157, 12), 256, 0, stream>>>(embb, ncb, wqkv, ipb, kbuf, vtb, qb, QSC);
  attn_k<<<dim3(NSPLIT, B_TOT / 128, NHEAD), 256, 0, stream>>>(qb, kbuf, vtb, pmT, pc, pl);
  combine_out<<<B_TOT, 256, 0, stream>>>(pc, pl, vtb, opw, opb, out);
}

// Round 19
// 106.920 us; speedup vs baseline: 1.1977x; 1.1977x over previous
//
#include <hip/hip_runtime.h>

typedef unsigned int uint_t;
typedef unsigned long long u64;
typedef unsigned short u16;
typedef __attribute__((ext_vector_type(4))) float f32x4;
typedef __attribute__((ext_vector_type(16))) float f32x16;
typedef __attribute__((ext_vector_type(8))) __bf16 bf16x8;

#define S_TOT 20000
#define S_LD  20032   // padded V^T row stride / padded K rows
#define B_TOT 1024
#define NHEAD 4
#define NSPLIT 32
#define NCHUNK 313    // ceil(20000/64)
#define NGRP   79     // ceil(20000/256) pack groups (4 chunks each)

__device__ __forceinline__ u16 f2bf(float x) {
  uint_t u = __builtin_bit_cast(uint_t, x);
  u += 0x7FFFu + ((u >> 16) & 1u);
  return (u16)(u >> 16);
}

__device__ __forceinline__ uint_t cvtpk(float lo, float hi) {
  uint_t r;
  asm("v_cvt_pk_bf16_f32 %0, %1, %2" : "=v"(r) : "v"(lo), "v"(hi));
  return r;
}

__device__ __forceinline__ bf16x8 ld_frag(const void* p) {
  return __builtin_bit_cast(bf16x8, *(const uint4*)p);
}

__device__ __forceinline__ void gload_lds16(const void* g, void* l) {
  __builtin_amdgcn_global_load_lds((const __attribute__((address_space(1))) unsigned int*)g,
                                   (__attribute__((address_space(3))) unsigned int*)l, 16, 0, 0);
}

// ---------------- fused prep: weight/nc/emb convert + mask pack (int4) + vt pad zero --------
__global__ void pack_conv(const int* __restrict__ act, u64* __restrict__ pmT,
                          const float* __restrict__ ipw, const float* __restrict__ opw,
                          const float* __restrict__ nc, const float* __restrict__ emb,
                          u16* __restrict__ wqkv, u16* __restrict__ wout, u16* __restrict__ ncb,
                          u16* __restrict__ embb, u16* __restrict__ vt) {
  const int bx = blockIdx.x;
  if (bx < 5512) {
    const float* src; u16* dst;
    if (bx < 512) {
      int i = (bx * 256 + threadIdx.x) * 4;
      if (i < 196608)      { src = ipw + i;            dst = wqkv + i; }
      else if (i < 262144) { src = opw + (i - 196608); dst = wout + (i - 196608); }
      else                 { src = nc  + (i - 262144); dst = ncb  + (i - 262144); }
    } else {
      int i = ((bx - 512) * 256 + threadIdx.x) * 4;
      src = emb + i; dst = embb + i;
    }
    float4 v = *(const float4*)src;
    uint2 o;
    o.x = f2bf(v.x) | ((uint_t)f2bf(v.y) << 16);
    o.y = f2bf(v.z) | ((uint_t)f2bf(v.w) << 16);
    *(uint2*)dst = o;
    return;
  }
  if (bx < 25736) {
    const int gw = (bx - 5512) * 4 + (threadIdx.x >> 6);   // 0 .. 80896 = 1024 rows * 79 grps
    const int lane = threadIdx.x & 63;
    const int row = gw / NGRP, gi = gw - row * NGRP;
    const int s = gi * 256 + lane * 4;
    int4 v = make_int4(0, 0, 0, 0);
    if (s < S_TOT) v = *(const int4*)(act + (size_t)row * S_TOT + s);
    uint_t nib = (v.x > 0 ? 1u : 0u) | (v.y > 0 ? 2u : 0u) |
                 (v.z > 0 ? 4u : 0u) | (v.w > 0 ? 8u : 0u);
    u64 v64 = (u64)nib << (4 * (lane & 15));
    v64 |= __shfl_xor(v64, 1);
    v64 |= __shfl_xor(v64, 2);
    v64 |= __shfl_xor(v64, 4);
    v64 |= __shfl_xor(v64, 8);
    if ((lane & 15) == 0)     // lanes 0,16,32,48 -> chunks gi*4 + 0..3 (pmT padded to 316)
      pmT[(size_t)(gi * 4 + (lane >> 4)) * B_TOT + row] = v64;
    return;
  }
  int i = (bx - 25736) * 256 + threadIdx.x;       // 8192 = 256 rows * 32
  int d = i >> 5, j = i & 31;
  vt[(size_t)d * S_LD + S_TOT + j] = 0;
}

// ---------------- out-proj GEMM: C[1024 x 256] f32 ----------------
__launch_bounds__(256)
__global__ void gemm_bt(const u16* __restrict__ A, const u16* __restrict__ W,
                        const float* __restrict__ bias, int M,
                        float* __restrict__ of) {
  __shared__ __align__(16) u16 sA[64][40];
  __shared__ __align__(16) u16 sW[64][40];
  const int t = threadIdx.x;
  const int w = t >> 6, lane = t & 63, lr = lane & 15, lg = lane >> 4;
  const int m0 = blockIdx.x * 64, n0 = blockIdx.y * 64;
  const int r = t >> 2, kc = (t & 3) * 8;
  f32x4 acc[4] = {};
  int ga = m0 + r; if (ga > M - 1) ga = M - 1;
  const u16* ap = A + (size_t)ga * 256;
  const u16* wp = W + (size_t)(n0 + r) * 256;
  for (int k0 = 0; k0 < 256; k0 += 32) {
    *(uint4*)&sA[r][kc] = *(const uint4*)(ap + k0 + kc);
    *(uint4*)&sW[r][kc] = *(const uint4*)(wp + k0 + kc);
    __syncthreads();
    bf16x8 af = ld_frag(&sA[16 * w + lr][lg * 8]);
#pragma unroll
    for (int nf = 0; nf < 4; nf++) {
      bf16x8 bfr = ld_frag(&sW[16 * nf + lr][lg * 8]);
      acc[nf] = __builtin_amdgcn_mfma_f32_16x16x32_bf16(af, bfr, acc[nf], 0, 0, 0);
    }
    __syncthreads();
  }
  const int rbase = m0 + 16 * w + lg * 4;
#pragma unroll
  for (int nf = 0; nf < 4; nf++) {
    const int n = n0 + nf * 16 + lr;
    const float bi = bias[n];
#pragma unroll
    for (int g = 0; g < 4; g++)
      if (rbase + g < M) of[(size_t)(rbase + g) * 256 + n] = acc[nf][g] + bi;
  }
}

// ---------------- KV + Q projection: fused 128x64-tile GEMM ----------------
// y in [0,8): C[20000 x 512] = embb @ Wkv^T + b  (K rows / V^T)
// y in [8,12): C[1024 x 256] = ncb @ Wq^T + b, scaled bf16 -> qb  (x < 8 only)
__launch_bounds__(256, 3)
__global__ void gemm_kvq(const u16* __restrict__ embb, const u16* __restrict__ ncb,
                         const u16* __restrict__ wqkv, const float* __restrict__ ipb,
                         u16* __restrict__ kb, u16* __restrict__ vtb, u16* __restrict__ qb,
                         float qsc) {
  const int by = blockIdx.y;
  const int qmode = (by >= 8);
  if (qmode && blockIdx.x >= 8) return;
  __shared__ __align__(16) u16 sA[2][128][64];
  __shared__ __align__(16) u16 sW[2][64][64];
  const int t = threadIdx.x, w = t >> 6, lane = t & 63;
  const int q5 = lane & 31, hi = lane >> 5;
  const int wr = w >> 1, wc = w & 1;
  const int m0 = blockIdx.x * 128;
  const int M = qmode ? B_TOT : S_TOT;
  const u16* A = qmode ? ncb : embb;
  const int wrow0 = qmode ? (by - 8) * 64 : 256 + by * 64;   // row base in wqkv
  const u16* W = wqkv + (size_t)wrow0 * 256;
  const float* bias = ipb + wrow0;

  auto stage = [&](int buf, int k0) {
#pragma unroll
    for (int j = 0; j < 4; j++) {           // A: 1024 16B-chunks
      int c = j * 256 + w * 64 + lane;
      int row = c >> 3, slot = c & 7;
      int gm = m0 + row; if (gm > M - 1) gm = M - 1;
      gload_lds16(A + (size_t)gm * 256 + k0 + ((slot ^ (row & 7)) * 8),
                  &sA[buf][0][0] + (size_t)(j * 256 + w * 64) * 8);
    }
#pragma unroll
    for (int j = 0; j < 2; j++) {           // W: 512 16B-chunks
      int c = j * 256 + w * 64 + lane;
      int row = c >> 3, slot = c & 7;
      gload_lds16(W + (size_t)row * 256 + k0 + ((slot ^ (row & 7)) * 8),
                  &sW[buf][0][0] + (size_t)(j * 256 + w * 64) * 8);
    }
  };

  f32x16 acc[2] = {{}, {}};
  stage(0, 0);
  __syncthreads();
  for (int ks = 0; ks < 4; ks++) {
    const int buf = ks & 1;
    if (ks < 3) stage(buf ^ 1, (ks + 1) * 64);
#pragma unroll
    for (int k4 = 0; k4 < 4; k4++) {
      const int rowW = wc * 32 + q5;
      bf16x8 wf = ld_frag(&sW[buf][rowW][((2 * k4 + hi) ^ (rowW & 7)) * 8]);
#pragma unroll
      for (int blk = 0; blk < 2; blk++) {
        const int rowA = wr * 64 + blk * 32 + q5;
        bf16x8 af = ld_frag(&sA[buf][rowA][((2 * k4 + hi) ^ (rowA & 7)) * 8]);
        acc[blk] = __builtin_amdgcn_mfma_f32_32x32x16_bf16(af, wf, acc[blk], 0, 0, 0);
      }
    }
    __syncthreads();
  }
  const int nl = wc * 32 + q5;              // local col within 64-tile
  const float bi = bias[nl];
  if (qmode) {
    const int n = (by - 8) * 64 + nl;       // 0..255
#pragma unroll
    for (int blk = 0; blk < 2; blk++)
#pragma unroll
      for (int r = 0; r < 16; r++) {
        int mrow = m0 + wr * 64 + blk * 32 + (r & 3) + 8 * (r >> 2) + 4 * hi;
        if (mrow < B_TOT) qb[(size_t)mrow * 256 + n] = f2bf((acc[blk][r] + bi) * qsc);
      }
    return;
  }
  const int n = by * 64 + nl;               // 0..511
  if (n < 256) {
#pragma unroll
    for (int blk = 0; blk < 2; blk++)
#pragma unroll
      for (int r = 0; r < 16; r++) {
        int mrow = m0 + wr * 64 + blk * 32 + (r & 3) + 8 * (r >> 2) + 4 * hi;
        if (mrow < S_TOT) kb[(size_t)mrow * 256 + n] = f2bf(acc[blk][r] + bi);
      }
  } else {
    const int vr = n - 256;
#pragma unroll
    for (int blk = 0; blk < 2; blk++)
#pragma unroll
      for (int g = 0; g < 4; g++) {
        int mb = m0 + wr * 64 + blk * 32 + 8 * g + 4 * hi;
        u16 b4[4];
#pragma unroll
        for (int j = 0; j < 4; j++) b4[j] = f2bf(acc[blk][4 * g + j] + bi);
        if (mb + 3 < S_TOT) {
          uint2 p2; p2.x = b4[0] | ((uint_t)b4[1] << 16); p2.y = b4[2] | ((uint_t)b4[3] << 16);
          *(uint2*)&vtb[(size_t)vr * S_LD + mb] = p2;
        } else {
#pragma unroll
          for (int j = 0; j < 4; j++) if (mb + j < S_TOT) vtb[(size_t)vr * S_LD + mb + j] = b4[j];
        }
      }
  }
}

// ---------------- flash attention: R13-exact body and layouts (proven 48.5 us) --------------
// Fixed-ref softmax; PV via permlane + 32x32x16; l = mfma(ones, P) -> accl[0].
// pc layout [si][b][h][d] (scattered 4B stores — measured optimal: WRITE ~= payload).
__launch_bounds__(256)
__attribute__((amdgpu_waves_per_eu(4, 4)))
__global__ void attn_k(const u16* __restrict__ qb, const u16* __restrict__ kb,
                       const u16* __restrict__ vt, const u64* __restrict__ pmT,
                       float* __restrict__ pc, float* __restrict__ pl) {
  __shared__ __align__(16) u16 sK[2][64][64];
  __shared__ __align__(16) u16 sV[2][64][64];
  const int t = threadIdx.x;
  const int w = t >> 6, lane = t & 63;
  const int q5 = lane & 31, hi = lane >> 5;
  const int si = blockIdx.x, bt = blockIdx.y, h = blockIdx.z;
  const int qrow = bt * 128 + w * 32 + q5;

  bf16x8 qf[4];
#pragma unroll
  for (int kc = 0; kc < 4; kc++)
    qf[kc] = ld_frag(qb + (size_t)qrow * 256 + h * 64 + kc * 16 + hi * 8);

  f32x16 ctx[2] = {{}, {}};
  f32x16 accl = {};                          // ones-row denominator accumulator
  const uint_t one2 = 0x3F803F80u;           // 2 x bf16 1.0
  uint4 onesw; onesw.x = one2; onesw.y = one2; onesw.z = one2; onesw.w = one2;
  const bf16x8 onesf = __builtin_bit_cast(bf16x8, onesw);

  const int rg = w * 16 + (lane >> 3);
  const int c16 = (lane & 7) ^ ((lane >> 3) & 7);
  const u16* kst = kb + (size_t)(si * 64 + rg) * 256 + h * 64 + c16 * 8;
  const u16* vst = vt + (size_t)(h * 64 + rg) * S_LD + si * 64 + c16 * 8;
  const u64* mptr = pmT + (size_t)si * B_TOT + qrow;
  const size_t KSTEP = (size_t)NSPLIT * 64 * 256;
  const int    VSTEP = NSPLIT * 64;
  const size_t MSTEP = (size_t)NSPLIT * B_TOT;

  auto stage = [&](int buf) {
    gload_lds16(kst,            &sK[buf][w * 16][0]);
    gload_lds16(kst + 8 * 256,  &sK[buf][w * 16 + 8][0]);
    gload_lds16(vst,            &sV[buf][w * 16][0]);
    gload_lds16(vst + 8 * S_LD, &sV[buf][w * 16 + 8][0]);
    kst += KSTEP; vst += VSTEP;
  };

  auto body = [&](int buf) {
    const u64 m64 = *mptr; mptr += MSTEP;
    f32x16 sc0 = {}, sc1 = {};
#pragma unroll
    for (int kc = 0; kc < 4; kc++) {
      const int slot = ((2 * kc + hi) ^ (q5 & 7)) * 8;
      bf16x8 ka0 = ld_frag(&sK[buf][q5][slot]);
      bf16x8 ka1 = ld_frag(&sK[buf][32 + q5][slot]);
      sc0 = __builtin_amdgcn_mfma_f32_32x32x16_bf16(ka0, qf[kc], sc0, 0, 0, 0);
      sc1 = __builtin_amdgcn_mfma_f32_32x32x16_bf16(ka1, qf[kc], sc1, 0, 0, 0);
    }
    const uint_t mw0 = (uint_t)(m64 >> (4 * hi));
    const uint_t mw1 = (uint_t)(m64 >> (32 + 4 * hi));
#pragma unroll
    for (int r = 0; r < 16; r++) {
      const uint_t bsel = 1u << ((r & 3) + 8 * (r >> 2));
      sc0[r] = (mw0 & bsel) ? sc0[r] : -1e9f;
      sc1[r] = (mw1 & bsel) ? sc1[r] : -1e9f;
    }
    uint2 pk[2][4];
#pragma unroll
    for (int j = 0; j < 4; j++) {
      float a0 = exp2f(sc0[4 * j + 0]), a1 = exp2f(sc0[4 * j + 1]);
      float a2 = exp2f(sc0[4 * j + 2]), a3 = exp2f(sc0[4 * j + 3]);
      float b0 = exp2f(sc1[4 * j + 0]), b1 = exp2f(sc1[4 * j + 1]);
      float b2 = exp2f(sc1[4 * j + 2]), b3 = exp2f(sc1[4 * j + 3]);
      pk[0][j].x = cvtpk(a0, a1); pk[0][j].y = cvtpk(a2, a3);
      pk[1][j].x = cvtpk(b0, b1); pk[1][j].y = cvtpk(b2, b3);
    }
    const u16* Vrow = &sV[buf][q5][0];
#pragma unroll
    for (int u = 0; u < 4; u++) {
      const int b = u >> 1, v = u & 1;
      uint_t a0 = pk[b][2 * v].x,     a1 = pk[b][2 * v].y;
      uint_t b0 = pk[b][2 * v + 1].x, b1 = pk[b][2 * v + 1].y;
      asm("v_permlane32_swap_b32 %0, %1" : "+v"(a0), "+v"(b0));
      asm("v_permlane32_swap_b32 %0, %1" : "+v"(a1), "+v"(b1));
      uint4 bw; bw.x = a0; bw.y = a1; bw.z = b0; bw.w = b1;
      bf16x8 pfrag = __builtin_bit_cast(bf16x8, bw);
      const int slot = ((2 * u + hi) ^ (q5 & 7)) * 8;   // u16 units (16B slots)
      bf16x8 va0 = ld_frag(Vrow + slot);
      bf16x8 va1 = ld_frag(Vrow + 32 * 64 + slot);      // row q5+32
      ctx[0] = __builtin_amdgcn_mfma_f32_32x32x16_bf16(va0, pfrag, ctx[0], 0, 0, 0);
      ctx[1] = __builtin_amdgcn_mfma_f32_32x32x16_bf16(va1, pfrag, ctx[1], 0, 0, 0);
      accl   = __builtin_amdgcn_mfma_f32_32x32x16_bf16(onesf, pfrag, accl, 0, 0, 0);
    }
  };

  stage(0);
  __syncthreads();
  int ci = si;
  for (;;) {
    if (ci + NSPLIT < NCHUNK) stage(1);
    body(0);
    __syncthreads();
    ci += NSPLIT;
    if (ci >= NCHUNK) break;
    if (ci + NSPLIT < NCHUNK) stage(0);
    body(1);
    __syncthreads();
    ci += NSPLIT;
    if (ci >= NCHUNK) break;
  }

  size_t obase = (((size_t)si * B_TOT + qrow) * NHEAD + h) * 64;
#pragma unroll
  for (int dc = 0; dc < 2; dc++)
#pragma unroll
    for (int r = 0; r < 16; r++) {
      int d = dc * 32 + (r & 3) + 8 * (r >> 2) + 4 * hi;
      pc[obase + d] = ctx[dc][r];
    }
  if (lane < 32)
    pl[((size_t)si * B_TOT + qrow) * NHEAD + h] = accl[0];   // l = sum of rounded p
}

// ---------------- combine: pure sums + lazy exact v_mean (R13-exact) ----------------
__global__ void combine_k(const float* __restrict__ pc, const float* __restrict__ pl,
                          const u16* __restrict__ vtb, u16* __restrict__ ctxb) {
  const int b = blockIdx.x, t = threadIdx.x;
  const int h = t >> 6, d = t & 63;
  float L = 0.f, a = 0.f;
#pragma unroll 8
  for (int si = 0; si < NSPLIT; si++) {
    size_t base = ((size_t)si * B_TOT + b) * NHEAD + h;
    L += pl[base];
    a += pc[(base << 6) + d];
  }
  float vmv = 0.f;
  if (__builtin_expect(L == 0.f, 0)) {   // exact fallback; never taken for this data
    float s = 0.f;
    for (int c = 0; c < 2504; c++) {
      bf16x8 v = ld_frag(vtb + (size_t)(h * 64 + d) * S_LD + c * 8);
#pragma unroll
      for (int i = 0; i < 8; i++) s += (float)v[i];
    }
    vmv = s * (1.0f / 20000.0f);
  }
  float r = (L == 0.f) ? vmv : (a / L);
  ctxb[(size_t)b * 256 + t] = f2bf(r);
}

// ---------------- launch ----------------
extern "C" void kernel_launch(void* const* d_in, const int* in_sizes, int n_in,
                              void* d_out, int out_size, void* d_ws, size_t ws_size,
                              hipStream_t stream) {
  const int*   act = (const int*)d_in[0];
  const float* nc  = (const float*)d_in[1];
  const float* emb = (const float*)d_in[2];
  const float* ipw = (const float*)d_in[3];
  const float* ipb = (const float*)d_in[4];
  const float* opw = (const float*)d_in[5];
  const float* opb = (const float*)d_in[6];
  float* out = (float*)d_out;
  char* ws = (char*)d_ws;

  size_t off = 0;
  auto alloc = [&](size_t bytes) { size_t r0 = off; off = (off + bytes + 255) & ~(size_t)255; return r0; };
  u16*   wqkv = (u16*)(ws + alloc(768 * 256 * 2));
  u16*   wout = (u16*)(ws + alloc(256 * 256 * 2));
  u16*   ncb  = (u16*)(ws + alloc((size_t)B_TOT * 256 * 2));
  u16*   qb   = (u16*)(ws + alloc((size_t)B_TOT * 256 * 2));
  u16*   kbuf = (u16*)(ws + alloc((size_t)S_LD * 256 * 2));   // padded rows
  u16*   vtb  = (u16*)(ws + alloc((size_t)256 * S_LD * 2));
  float* pl   = (float*)(ws + alloc((size_t)NSPLIT * B_TOT * NHEAD * 4));
  u16*   ctxb = (u16*)(ws + alloc((size_t)B_TOT * 256 * 2));
  u64*   pmT  = (u64*)(ws + alloc((size_t)NGRP * 4 * B_TOT * 8));  // 316 chunks (tail pad)
  // union region: embb (10.25 MB, dead after kv-projection) overlaid by pc (33.6 MB)
  size_t ubase = off;
  u16*   embb = (u16*)(ws + ubase);
  float* pc   = (float*)(ws + ubase);

  const float QSC = 0.125f * 1.44269504089f;   // (1/sqrt(64)) * log2(e), folded into Q

  pack_conv<<<25768, 256, 0, stream>>>(act, pmT, ipw, opw, nc, emb, wqkv, wout, ncb, embb, vtb);
  gemm_kvq<<<dim3(157, 12), 256, 0, stream>>>(embb, ncb, wqkv, ipb, kbuf, vtb, qb, QSC);
  attn_k<<<dim3(NSPLIT, B_TOT / 128, NHEAD), 256, 0, stream>>>(qb, kbuf, vtb, pmT, pc, pl);
  combine_k<<<B_TOT, 256, 0, stream>>>(pc, pl, vtb, ctxb);
  gemm_bt<<<dim3(16, 4), 256, 0, stream>>>(ctxb, wout, opb, B_TOT, out);
}